// Round 9
// baseline (591.395 us; speedup 1.0000x reference)
//
#include <hip/hip_runtime.h>

#define NN 50000
#define NE 600000
#define DD 128
#define ETILES (NE/64)        // 9375
#define NTILES ((NN+63)/64)   // 782
#define EB 1875               // edge blocks; 5 tiles each
#define TPB 5

typedef __attribute__((ext_vector_type(8))) short short8;
typedef __attribute__((ext_vector_type(4))) short s16x4;
typedef __attribute__((ext_vector_type(4))) float f32x4;
typedef __attribute__((ext_vector_type(2))) float f32x2;
typedef unsigned short u16;

#define MFMA16(a,b,c) __builtin_amdgcn_mfma_f32_16x16x32_bf16((a),(b),(c),0,0,0)

// raw barrier: LDS-ordering only (no vmcnt drain -> atomics/gathers stay in flight)
#define BAR() do{ __builtin_amdgcn_sched_barrier(0); \
  asm volatile("s_waitcnt lgkmcnt(0)" ::: "memory"); \
  __builtin_amdgcn_s_barrier(); \
  __builtin_amdgcn_sched_barrier(0);}while(0)

// ws layout:
//   u16 WF[131072]   bytes [0, 262144)            weight fragments
//   u16 XBF[6400000] bytes [262144, 13062144)     bf16 copy of x
#define XBF_U   131072
// int-element offsets within d_ws:
#define CNT_I   3265536   // int cnt[50000]
#define BSUM_I  3315536   // int bsum[256]
#define CUR_I   3315792   // int cursor/excl[50000]
#define ISORT_I 3365792   // int isorted[600000]
#define JSORT_I 3965792   // int jsorted[600000]

// edge LDS layout (bytes) — total 50688 so 3 blocks/CU fit (3x50688=152064
// <= 160KiB with ~11KB slack; R8's 53248x3=159744 evidently didn't co-schedule,
// occupancy stuck at 2 blocks). IDX slabs removed: sorted iso/jso are read
// directly from global (contiguous, L2-hot).
#define A_OFF    0        // bf16 [64][256] swizzled; later h1
#define H_OFF    32768    // bf16 [64][128] swizzled; h0 then h2
#define F4_OFF   49152    // f32 [64][4] d0,d1,d2,norm
#define SMR_OFF  50176    // float2 [64] (mean, rstd)
#define LDS_SZ   50688

__device__ __forceinline__ float bf2f(unsigned int u){
  union { unsigned int i; float f; } v; v.i = u << 16; return v.f;
}
__device__ __forceinline__ u16 f2bf(float f){
  union { float f; unsigned int i; } v; v.f = f;
  unsigned int r = v.i + 0x7fffu + ((v.i >> 16) & 1u);   // RNE
  return (u16)(r >> 16);
}
__device__ __forceinline__ int addrA(int row, int col){   // row stride 512B
  return (row<<9) + (((col>>3) ^ (row&7))<<4) + ((col&7)<<1);
}
__device__ __forceinline__ int addrH(int row, int col){   // row stride 256B
  return (row<<8) + (((col>>3) ^ (row&7))<<4) + ((col&7)<<1);
}

// ---- x -> bf16 cache -------------------------------------------------------
__global__ void k_xbf(const float* __restrict__ x, u16* __restrict__ xbf){
  const int i = blockIdx.x*256 + threadIdx.x;
  float4 a = ((const float4*)x)[i*2], b = ((const float4*)x)[i*2+1];
  short8 pk;
  pk[0]=(short)f2bf(a.x); pk[1]=(short)f2bf(a.y);
  pk[2]=(short)f2bf(a.z); pk[3]=(short)f2bf(a.w);
  pk[4]=(short)f2bf(b.x); pk[5]=(short)f2bf(b.y);
  pk[6]=(short)f2bf(b.z); pk[7]=(short)f2bf(b.w);
  ((short8*)xbf)[i] = pk;
}

// ---- combined repack: fp32 [K][128] -> bf16 MFMA B-fragments ---------------
__global__ void repack_all(const float* __restrict__ ew0, const float* __restrict__ ew1,
                           const float* __restrict__ ew2, const float* __restrict__ nw0,
                           const float* __restrict__ nw1, const float* __restrict__ nw2,
                           u16* __restrict__ ws){
  int b = blockIdx.x;
  const float* W; u16* out; int roff = 0;
  if      (b <  64){ W=ew0; out=ws;          roff=4; }
  else if (b <  96){ W=ew1; out=ws+ 32768; b-= 64; }
  else if (b < 128){ W=ew2; out=ws+ 49152; b-= 96; }
  else if (b < 192){ W=nw0; out=ws+ 65536; b-=128; }
  else if (b < 224){ W=nw1; out=ws+ 98304; b-=192; }
  else             { W=nw2; out=ws+114688; b-=224; }
  const int l = threadIdx.x;
  const int kk = b >> 3, cg = b & 7;
  const int kbase = kk*32 + ((l>>4)<<3) + roff;
  const int c = (cg<<4) + (l&15);
  short8 pk;
#pragma unroll
  for (int i=0;i<8;++i) pk[i] = (short)f2bf(W[(size_t)(kbase+i)*DD + c]);
  ((short8*)out)[b*64 + l] = pk;
}

// ---- counting sort of edges by destination j -------------------------------
__global__ void k_hist(const int* __restrict__ gJ, int* __restrict__ cnt){
  int e = blockIdx.x*256 + threadIdx.x;
  if (e < NE) atomicAdd(&cnt[gJ[e]], 1);
}
__global__ void k_scan1(const int* __restrict__ cnt, int* __restrict__ exc,
                        int* __restrict__ bsum){
  __shared__ int s[256];
  const int t = threadIdx.x, i = blockIdx.x*256 + t;
  int v = (i < NN) ? cnt[i] : 0;
  s[t] = v; __syncthreads();
#pragma unroll
  for (int off=1; off<256; off<<=1){
    int u = (t >= off) ? s[t-off] : 0; __syncthreads();
    s[t] += u; __syncthreads();
  }
  if (i < NN) exc[i] = s[t] - v;
  if (t == 255) bsum[blockIdx.x] = s[255];
}
__global__ void k_scan2(int* __restrict__ bsum){
  __shared__ int s[256];
  const int t = threadIdx.x;
  int v = (t < 196) ? bsum[t] : 0;
  s[t] = v; __syncthreads();
#pragma unroll
  for (int off=1; off<256; off<<=1){
    int u = (t >= off) ? s[t-off] : 0; __syncthreads();
    s[t] += u; __syncthreads();
  }
  if (t < 196) bsum[t] = s[t] - v;   // exclusive
}
__global__ void k_scan3(int* __restrict__ exc, const int* __restrict__ bsum){
  const int i = blockIdx.x*256 + threadIdx.x;
  if (i < NN) exc[i] += bsum[blockIdx.x];
}
__global__ void k_perm(const int* __restrict__ gI, const int* __restrict__ gJ,
                       int* __restrict__ cur, int* __restrict__ iso,
                       int* __restrict__ jso){
  int e = blockIdx.x*256 + threadIdx.x;
  if (e < NE){
    int j = gJ[e];
    int p = atomicAdd(&cur[j], 1);
    iso[p] = gI[e]; jso[p] = j;
  }
}

// one MLP layer's MFMA sweep (setprio: with 3 independently-phased blocks/CU,
// boost the MFMA-issuing wave over staging/LN waves — T5)
template<int SH, int KK>
__device__ __forceinline__ void layer_mm(const unsigned char* lbase,
                                         const short8 (*wf)[2],
                                         f32x4 (&acc)[4][2],
                                         int l15, int l4){
  __builtin_amdgcn_s_setprio(1);
#pragma unroll
  for (int kk=0; kk<KK; ++kk){
    short8 a[4];
#pragma unroll
    for (int m=0;m<4;++m){
      const int row = m*16 + l15;
      const int col = kk*32 + l4*8;
      const int c = (col>>3) ^ (row&7);
      a[m] = *(const short8*)(lbase + (row<<SH) + (c<<4));
    }
#pragma unroll
    for (int m=0;m<4;++m){
      acc[m][0] = MFMA16(a[m], wf[kk][0], acc[m][0]);
      acc[m][1] = MFMA16(a[m], wf[kk][1], acc[m][1]);
    }
  }
  __builtin_amdgcn_s_setprio(0);
}
__device__ __forceinline__ void zero_acc(f32x4 (&acc)[4][2]){
#pragma unroll
  for (int m=0;m<4;++m)
#pragma unroll
    for (int n=0;n<2;++n){ f32x4 z = {0.f,0.f,0.f,0.f}; acc[m][n] = z; }
}
// C/D mapping: col = lane&15, row = (lane>>4)*4 + reg
__device__ __forceinline__ void store_h(unsigned char* hbase, f32x4 (&acc)[4][2],
                                        const float* b, bool relu,
                                        int w, int l15, int l4){
#pragma unroll
  for (int m=0;m<4;++m)
#pragma unroll
    for (int r=0;r<4;++r){
      const int row = m*16 + l4*4 + r;
#pragma unroll
      for (int n=0;n<2;++n){
        float v = acc[m][n][r] + b[n];
        if (relu) v = fmaxf(v, 0.f);
        *(u16*)(hbase + addrH(row, w*32 + n*16 + l15)) = f2bf(v);
      }
    }
}

// parallel 16-row LN stats: lane (l&15)=row offset, (l>>4)=32-col block.
__device__ __forceinline__ void ln_stats(unsigned char* lds_, int w, int l15, int l4){
  const int row = w*16 + l15;
  float s = 0.f, qs = 0.f;
#pragma unroll
  for (int q=0; q<4; ++q){
    short8 v8 = *(const short8*)(lds_ + H_OFF + addrH(row, l4*32 + q*8));
#pragma unroll
    for (int e2=0; e2<8; ++e2){
      float f = bf2f((u16)v8[e2]);
      s += f; qs += f*f;
    }
  }
  s  += __shfl_xor(s, 16);  qs += __shfl_xor(qs, 16);
  s  += __shfl_xor(s, 32);  qs += __shfl_xor(qs, 32);
  if (l4 == 0){
    float mean = s * (1.f/128.f);
    float var  = qs * (1.f/128.f) - mean*mean;
    float rstd = rsqrtf(var + 1e-5f);
    *(float2*)(lds_ + SMR_OFF + row*8) = make_float2(mean, rstd);
  }
}

// ---------------- edge kernel (sorted-by-j edges) ----------------
// launch_bounds(256,2): VGPR cap 256 — kernel needs ~128 arch VGPRs
// ((256,3) capped at ~85 and spilled weight frags to scratch: R3-R6's 1GB/launch).
__global__ __launch_bounds__(256, 2)
void edge_kernel(const u16* __restrict__ xbf, const float* __restrict__ pos,
                 const int* __restrict__ iso, const int* __restrict__ jso,
                 const short8* __restrict__ wf0, const short8* __restrict__ wf1,
                 const short8* __restrict__ wf2,
                 const float* __restrict__ ew0_raw,
                 const float* __restrict__ eb0, const float* __restrict__ eb1,
                 const float* __restrict__ eb2, const float* __restrict__ eg,
                 const float* __restrict__ ebeta,
                 float* aggr)
{
  __shared__ alignas(16) unsigned char lds[LDS_SZ];
  const int tid = threadIdx.x;
  const int w = tid >> 6, lane = tid & 63;
  const int l15 = lane & 15, l4 = lane >> 4;
  const int h = lane >> 5, l31 = lane & 31;

  short8 w0f[8][2], w1f[4][2], w2f[4][2];
#pragma unroll
  for (int kk=0;kk<8;++kk){
    w0f[kk][0] = wf0[(kk*8 + w*2    )*64 + lane];
    w0f[kk][1] = wf0[(kk*8 + w*2 + 1)*64 + lane];
  }
#pragma unroll
  for (int kk=0;kk<4;++kk){
    w1f[kk][0] = wf1[(kk*8 + w*2    )*64 + lane];
    w1f[kk][1] = wf1[(kk*8 + w*2 + 1)*64 + lane];
    w2f[kk][0] = wf2[(kk*8 + w*2    )*64 + lane];
    w2f[kk][1] = wf2[(kk*8 + w*2 + 1)*64 + lane];
  }
  float w4c[2][4];
#pragma unroll
  for (int n=0;n<2;++n)
#pragma unroll
    for (int q=0;q<4;++q) w4c[n][q] = ew0_raw[q*DD + w*32 + n*16 + l15];
  const float b0c[2] = { eb0[w*32 + l15], eb0[w*32 + 16 + l15] };
  const float b1c[2] = { eb1[w*32 + l15], eb1[w*32 + 16 + l15] };
  const float b2c[2] = { eb2[w*32 + l15], eb2[w*32 + 16 + l15] };
  const float egA = eg[2*lane],    egB = eg[2*lane+1];
  const float ebA = ebeta[2*lane], ebB = ebeta[2*lane+1];

  // bijective chunked XCD swizzle (m204)
  const int p = blockIdx.x;
  const int qq_ = EB/8, rr_ = EB%8;            // 234, 3
  const int xcd = p & 7, bidx = p >> 3;
  const int lb = (xcd < rr_ ? xcd*(qq_+1) : rr_*(qq_+1) + (xcd-rr_)*qq_) + bidx;
  const int ebase = lb*TPB*64;                 // block's 320 contiguous sorted edges

  // --- prologue: stage tile 0 (gather -> LDS directly; indices from global) ---
  {
#pragma unroll
    for (int it=0; it<16; ++it){
      const int slab = ebase + w*16 + it;
      const int ridx = h ? jso[slab] : iso[slab];
      s16x4 v = ((const s16x4*)(xbf + (size_t)ridx*DD))[l31];
      *(s16x4*)(lds + A_OFF + addrA(w*16+it, h*128 + l31*4)) = v;
    }
    if (tid < 64){
      const int ii = iso[ebase + tid], jj = jso[ebase + tid];
      float d0=pos[ii*3]-pos[jj*3], d1=pos[ii*3+1]-pos[jj*3+1], d2=pos[ii*3+2]-pos[jj*3+2];
      float nr=sqrtf(d0*d0+d1*d1+d2*d2);
      *(float4*)(lds + F4_OFF + tid*16) = make_float4(d0,d1,d2,nr);
    }
  }
  BAR();

  float a0 = 0.f, a1 = 0.f; int cj = -1;

  for (int tt = 0; tt < TPB; ++tt){
    f32x4 acc[4][2];
    // ---- P1: L0 (A + rank-4 pos part -> h0)
    zero_acc(acc);
    layer_mm<9,8>(lds + A_OFF, w0f, acc, l15, l4);
#pragma unroll
    for (int m=0;m<4;++m)
#pragma unroll
      for (int r=0;r<4;++r){
        const int row = m*16 + l4*4 + r;
        float4 f = *(const float4*)(lds + F4_OFF + row*16);
#pragma unroll
        for (int n=0;n<2;++n)
          acc[m][n][r] += f.x*w4c[n][0] + f.y*w4c[n][1] + f.z*w4c[n][2] + f.w*w4c[n][3];
      }
    store_h(lds + H_OFF, acc, b0c, true, w, l15, l4);
    BAR();
    // ---- P2: L1 (h0 -> h1 in A region)
    zero_acc(acc);
    layer_mm<8,4>(lds + H_OFF, w1f, acc, l15, l4);
    store_h(lds + A_OFF, acc, b1c, true, w, l15, l4);
    BAR();
    // ---- P3: L2 (h1 -> h2 in H region)
    zero_acc(acc);
    layer_mm<8,4>(lds + A_OFF, w2f, acc, l15, l4);
    store_h(lds + H_OFF, acc, b2c, false, w, l15, l4);
    BAR();
    // ---- P4: stage next tile (A region free; overlaps LN VALU work),
    //          parallel LN stats, batched o-compute, run-merged flush
    if (tt+1 < TPB){
      const int nb = ebase + (tt+1)*64;
#pragma unroll
      for (int it=0; it<16; ++it){
        const int slab = nb + w*16 + it;
        const int ridx = h ? jso[slab] : iso[slab];
        s16x4 v = ((const s16x4*)(xbf + (size_t)ridx*DD))[l31];
        *(s16x4*)(lds + A_OFF + addrA(w*16+it, h*128 + l31*4)) = v;
      }
      if (tid < 64){
        const int ii = iso[nb + tid], jj = jso[nb + tid];
        float d0=pos[ii*3]-pos[jj*3], d1=pos[ii*3+1]-pos[jj*3+1], d2=pos[ii*3+2]-pos[jj*3+2];
        float nr=sqrtf(d0*d0+d1*d1+d2*d2);
        *(float4*)(lds + F4_OFF + tid*16) = make_float4(d0,d1,d2,nr);
      }
    }
    ln_stats(lds, w, l15, l4);
#pragma unroll
    for (int half=0; half<2; ++half){
      float o0a[8], o1a[8]; int jja[8];
#pragma unroll
      for (int rr=0; rr<8; ++rr){
        const int row = w*16 + half*8 + rr;
        unsigned pk = *(const unsigned*)(lds + H_OFF + addrH(row, 2*lane));
        float2 mr = *(const float2*)(lds + SMR_OFF + row*8);
        float v0 = bf2f(pk & 0xffffu), v1 = bf2f(pk >> 16);
        o0a[rr] = (v0 - mr.x)*mr.y*egA + ebA;
        o1a[rr] = (v1 - mr.x)*mr.y*egB + ebB;
        jja[rr] = jso[ebase + tt*64 + row];      // wave-uniform, L2-hot
      }
#pragma unroll
      for (int rr=0; rr<8; ++rr){
        const int jj = jja[rr];
        if (jj != cj){
          if (cj >= 0){
            float* dst = aggr + (size_t)cj*DD + 2*lane;
            unsafeAtomicAdd(dst,     a0);
            unsafeAtomicAdd(dst + 1, a1);
          }
          cj = jj; a0 = o0a[rr]; a1 = o1a[rr];
        } else { a0 += o0a[rr]; a1 += o1a[rr]; }
      }
    }
    BAR();
  }
  if (cj >= 0){
    float* dst = aggr + (size_t)cj*DD + 2*lane;
    unsafeAtomicAdd(dst,     a0);
    unsafeAtomicAdd(dst + 1, a1);
  }
}

// ---------------- node kernel ----------------
#define SMR_OFF_N 49152
__global__ __launch_bounds__(256, 2)
void node_kernel(const u16* __restrict__ xbf, const float* __restrict__ x,
                 const short8* __restrict__ wf0, const short8* __restrict__ wf1,
                 const short8* __restrict__ wf2,
                 const float* __restrict__ nb0, const float* __restrict__ nb1,
                 const float* __restrict__ nb2, const float* __restrict__ ng,
                 const float* __restrict__ nbeta,
                 float* nio)
{
  __shared__ alignas(16) unsigned char lds[49664];
  const int tid = threadIdx.x;
  const int w = tid >> 6, lane = tid & 63;
  const int l15 = lane & 15, l4 = lane >> 4;
  const int h = lane >> 5, l31 = lane & 31;

  short8 w0f[8][2], w1f[4][2], w2f[4][2];
#pragma unroll
  for (int kk=0;kk<8;++kk){
    w0f[kk][0] = wf0[(kk*8 + w*2    )*64 + lane];
    w0f[kk][1] = wf0[(kk*8 + w*2 + 1)*64 + lane];
  }
#pragma unroll
  for (int kk=0;kk<4;++kk){
    w1f[kk][0] = wf1[(kk*8 + w*2    )*64 + lane];
    w1f[kk][1] = wf1[(kk*8 + w*2 + 1)*64 + lane];
    w2f[kk][0] = wf2[(kk*8 + w*2    )*64 + lane];
    w2f[kk][1] = wf2[(kk*8 + w*2 + 1)*64 + lane];
  }
  const float b0c[2] = { nb0[w*32 + l15], nb0[w*32 + 16 + l15] };
  const float b1c[2] = { nb1[w*32 + l15], nb1[w*32 + 16 + l15] };
  const float b2c[2] = { nb2[w*32 + l15], nb2[w*32 + 16 + l15] };
  const float ngA = ng[2*lane],    ngB = ng[2*lane+1];
  const float nbA = nbeta[2*lane], nbB = nbeta[2*lane+1];

  for (int t = blockIdx.x; t < NTILES; t += gridDim.x){
    const int n0 = t*64;
#pragma unroll
    for (int it=0; it<16; ++it){
      const int rloc = w*16 + it;
      const int row = n0 + rloc;
      s16x4 v;
      if (h == 0){
        if (row < NN) v = ((const s16x4*)(xbf + (size_t)row*DD))[l31];
        else { v[0]=0; v[1]=0; v[2]=0; v[3]=0; }
      } else {
        if (row < NN){
          float4 f = ((const float4*)(nio + (size_t)row*DD))[l31];
          v[0]=(short)f2bf(f.x); v[1]=(short)f2bf(f.y);
          v[2]=(short)f2bf(f.z); v[3]=(short)f2bf(f.w);
        } else { v[0]=0; v[1]=0; v[2]=0; v[3]=0; }
      }
      *(s16x4*)(lds + A_OFF + addrA(rloc, h*128 + l31*4)) = v;
    }
    __syncthreads();

    f32x4 acc[4][2];
    zero_acc(acc);
    layer_mm<9,8>(lds + A_OFF, w0f, acc, l15, l4);
    store_h(lds + H_OFF, acc, b0c, true, w, l15, l4);
    __syncthreads();
    zero_acc(acc);
    layer_mm<8,4>(lds + H_OFF, w1f, acc, l15, l4);
    store_h(lds + A_OFF, acc, b1c, true, w, l15, l4);
    __syncthreads();
    zero_acc(acc);
    layer_mm<8,4>(lds + A_OFF, w2f, acc, l15, l4);
    store_h(lds + H_OFF, acc, b2c, false, w, l15, l4);
    __syncthreads();
    // ---- parallel LN stats (write smr) then independent output rows
    {
      const int row = w*16 + l15;
      float s = 0.f, qs = 0.f;
#pragma unroll
      for (int q=0; q<4; ++q){
        short8 v8 = *(const short8*)(lds + H_OFF + addrH(row, l4*32 + q*8));
#pragma unroll
        for (int e2=0; e2<8; ++e2){
          float f = bf2f((u16)v8[e2]);
          s += f; qs += f*f;
        }
      }
      s  += __shfl_xor(s, 16);  qs += __shfl_xor(qs, 16);
      s  += __shfl_xor(s, 32);  qs += __shfl_xor(qs, 32);
      if (l4 == 0){
        float mean = s * (1.f/128.f);
        float var  = qs * (1.f/128.f) - mean*mean;
        float rstd = rsqrtf(var + 1e-5f);
        *(float2*)(lds + SMR_OFF_N + row*8) = make_float2(mean, rstd);
      }
    }
#pragma unroll
    for (int half=0; half<2; ++half){
#pragma unroll
      for (int rr=0; rr<8; ++rr){
        const int rloc = w*16 + half*8 + rr;
        const int row = n0 + rloc;
        if (row < NN){
          unsigned pk = *(const unsigned*)(lds + H_OFF + addrH(rloc, 2*lane));
          float2 mr = *(const float2*)(lds + SMR_OFF_N + rloc*8);
          f32x2 xr = *(const f32x2*)(x + (size_t)row*DD + 2*lane);
          float v0 = bf2f(pk & 0xffffu), v1 = bf2f(pk >> 16);
          f32x2 o;
          o[0] = (v0 - mr.x)*mr.y*ngA + nbA + xr[0];
          o[1] = (v1 - mr.x)*mr.y*ngB + nbB + xr[1];
          *(f32x2*)(nio + (size_t)row*DD + 2*lane) = o;
        }
      }
    }
    __syncthreads();
  }
}

extern "C" void kernel_launch(void* const* d_in, const int* in_sizes, int n_in,
                              void* d_out, int out_size, void* d_ws, size_t ws_size,
                              hipStream_t stream) {
  const float* x     = (const float*)d_in[0];
  const float* pos   = (const float*)d_in[1];
  const int*   g     = (const int*)  d_in[2];
  const float* ew0   = (const float*)d_in[3];
  const float* eb0   = (const float*)d_in[4];
  const float* ew1   = (const float*)d_in[5];
  const float* eb1   = (const float*)d_in[6];
  const float* ew2   = (const float*)d_in[7];
  const float* eb2   = (const float*)d_in[8];
  const float* eg    = (const float*)d_in[9];
  const float* ebeta = (const float*)d_in[10];
  const float* nw0   = (const float*)d_in[11];
  const float* nb0   = (const float*)d_in[12];
  const float* nw1   = (const float*)d_in[13];
  const float* nb1   = (const float*)d_in[14];
  const float* nw2   = (const float*)d_in[15];
  const float* nb2   = (const float*)d_in[16];
  const float* ng    = (const float*)d_in[17];
  const float* nbeta = (const float*)d_in[18];
  float* out  = (float*)d_out;
  u16*   ws   = (u16*)d_ws;
  int*   wsi  = (int*)d_ws;

  const int* gI = g;
  const int* gJ = g + NE;

  // x -> bf16 cache + weight fragment repack
  k_xbf<<<dim3(3125), dim3(256), 0, stream>>>(x, ws + XBF_U);
  repack_all<<<dim3(256), dim3(64), 0, stream>>>(ew0, ew1, ew2, nw0, nw1, nw2, ws);

  // counting sort of edges by j
  hipMemsetAsync(wsi + CNT_I, 0, NN*sizeof(int), stream);
  k_hist <<<dim3((NE+255)/256), dim3(256), 0, stream>>>(gJ, wsi + CNT_I);
  k_scan1<<<dim3(196), dim3(256), 0, stream>>>(wsi + CNT_I, wsi + CUR_I, wsi + BSUM_I);
  k_scan2<<<dim3(1), dim3(256), 0, stream>>>(wsi + BSUM_I);
  k_scan3<<<dim3(196), dim3(256), 0, stream>>>(wsi + CUR_I, wsi + BSUM_I);
  k_perm <<<dim3((NE+255)/256), dim3(256), 0, stream>>>(gI, gJ, wsi + CUR_I,
                                                        wsi + ISORT_I, wsi + JSORT_I);

  // aggr accumulator lives in d_out; zero it
  hipMemsetAsync(d_out, 0, (size_t)NN * DD * sizeof(float), stream);

  edge_kernel<<<dim3(EB), dim3(256), 0, stream>>>(
      ws + XBF_U, pos, wsi + ISORT_I, wsi + JSORT_I,
      (const short8*)(ws), (const short8*)(ws + 32768), (const short8*)(ws + 49152),
      ew0, eb0, eb1, eb2, eg, ebeta, out);

  node_kernel<<<dim3(NTILES), dim3(256), 0, stream>>>(
      ws + XBF_U, x,
      (const short8*)(ws + 65536), (const short8*)(ws + 98304), (const short8*)(ws + 114688),
      nb0, nb1, nb2, ng, nbeta, out);
}

// Round 11
// 495.137 us; speedup vs baseline: 1.1944x; 1.1944x over previous
//
#include <hip/hip_runtime.h>

#define NN 50000
#define NE 600000
#define DD 128
#define ETILES (NE/64)        // 9375
#define NTILES ((NN+63)/64)   // 782
#define EB 1875               // edge blocks; 5 tiles each
#define TPB 5

typedef __attribute__((ext_vector_type(8))) short short8;
typedef __attribute__((ext_vector_type(4))) short s16x4;
typedef __attribute__((ext_vector_type(4))) float f32x4;
typedef __attribute__((ext_vector_type(2))) float f32x2;
typedef unsigned short u16;

#define MFMA16(a,b,c) __builtin_amdgcn_mfma_f32_16x16x32_bf16((a),(b),(c),0,0,0)

// raw barrier: LDS-ordering only (no vmcnt drain -> atomics/gathers stay in flight)
#define BAR() do{ __builtin_amdgcn_sched_barrier(0); \
  asm volatile("s_waitcnt lgkmcnt(0)" ::: "memory"); \
  __builtin_amdgcn_s_barrier(); \
  __builtin_amdgcn_sched_barrier(0);}while(0)

// ws layout:
//   u16 WF[131072]   bytes [0, 262144)            weight fragments
//   u16 XBF[6400000] bytes [262144, 13062144)     bf16 copy of x
#define XBF_U   131072
// int-element offsets within d_ws:
#define CNT_I   3265536   // int cnt[50000]
#define BSUM_I  3315536   // int bsum[256]
#define CUR_I   3315792   // int cursor/excl[50000]
#define ISORT_I 3365792   // int isorted[600000]
#define JSORT_I 3965792   // int jsorted[600000]

// edge LDS layout (bytes), 50688 total (3 blocks x 50688 = 152 KB <= 160 KB)
#define A_OFF    0        // bf16 [64][256] swizzled; later h1
#define H_OFF    32768    // bf16 [64][128] swizzled; h0 then h2
#define F4_OFF   49152    // f32 [64][4] d0,d1,d2,norm
#define SMR_OFF  50176    // float2 [64] (mean, rstd)
#define LDS_SZ   50688

__device__ __forceinline__ float bf2f(unsigned int u){
  union { unsigned int i; float f; } v; v.i = u << 16; return v.f;
}
__device__ __forceinline__ u16 f2bf(float f){
  union { float f; unsigned int i; } v; v.f = f;
  unsigned int r = v.i + 0x7fffu + ((v.i >> 16) & 1u);   // RNE
  return (u16)(r >> 16);
}
__device__ __forceinline__ int addrA(int row, int col){   // row stride 512B
  return (row<<9) + (((col>>3) ^ (row&7))<<4) + ((col&7)<<1);
}
__device__ __forceinline__ int addrH(int row, int col){   // row stride 256B
  return (row<<8) + (((col>>3) ^ (row&7))<<4) + ((col&7)<<1);
}

// ---- x -> bf16 cache -------------------------------------------------------
__global__ void k_xbf(const float* __restrict__ x, u16* __restrict__ xbf){
  const int i = blockIdx.x*256 + threadIdx.x;
  float4 a = ((const float4*)x)[i*2], b = ((const float4*)x)[i*2+1];
  short8 pk;
  pk[0]=(short)f2bf(a.x); pk[1]=(short)f2bf(a.y);
  pk[2]=(short)f2bf(a.z); pk[3]=(short)f2bf(a.w);
  pk[4]=(short)f2bf(b.x); pk[5]=(short)f2bf(b.y);
  pk[6]=(short)f2bf(b.z); pk[7]=(short)f2bf(b.w);
  ((short8*)xbf)[i] = pk;
}

// ---- combined repack: fp32 [K][128] -> bf16 MFMA B-fragments ---------------
__global__ void repack_all(const float* __restrict__ ew0, const float* __restrict__ ew1,
                           const float* __restrict__ ew2, const float* __restrict__ nw0,
                           const float* __restrict__ nw1, const float* __restrict__ nw2,
                           u16* __restrict__ ws){
  int b = blockIdx.x;
  const float* W; u16* out; int roff = 0;
  if      (b <  64){ W=ew0; out=ws;          roff=4; }
  else if (b <  96){ W=ew1; out=ws+ 32768; b-= 64; }
  else if (b < 128){ W=ew2; out=ws+ 49152; b-= 96; }
  else if (b < 192){ W=nw0; out=ws+ 65536; b-=128; }
  else if (b < 224){ W=nw1; out=ws+ 98304; b-=192; }
  else             { W=nw2; out=ws+114688; b-=224; }
  const int l = threadIdx.x;
  const int kk = b >> 3, cg = b & 7;
  const int kbase = kk*32 + ((l>>4)<<3) + roff;
  const int c = (cg<<4) + (l&15);
  short8 pk;
#pragma unroll
  for (int i=0;i<8;++i) pk[i] = (short)f2bf(W[(size_t)(kbase+i)*DD + c]);
  ((short8*)out)[b*64 + l] = pk;
}

// ---- counting sort of edges by destination j -------------------------------
__global__ void k_hist(const int* __restrict__ gJ, int* __restrict__ cnt){
  int e = blockIdx.x*256 + threadIdx.x;
  if (e < NE) atomicAdd(&cnt[gJ[e]], 1);
}
__global__ void k_scan1(const int* __restrict__ cnt, int* __restrict__ exc,
                        int* __restrict__ bsum){
  __shared__ int s[256];
  const int t = threadIdx.x, i = blockIdx.x*256 + t;
  int v = (i < NN) ? cnt[i] : 0;
  s[t] = v; __syncthreads();
#pragma unroll
  for (int off=1; off<256; off<<=1){
    int u = (t >= off) ? s[t-off] : 0; __syncthreads();
    s[t] += u; __syncthreads();
  }
  if (i < NN) exc[i] = s[t] - v;
  if (t == 255) bsum[blockIdx.x] = s[255];
}
__global__ void k_scan2(int* __restrict__ bsum){
  __shared__ int s[256];
  const int t = threadIdx.x;
  int v = (t < 196) ? bsum[t] : 0;
  s[t] = v; __syncthreads();
#pragma unroll
  for (int off=1; off<256; off<<=1){
    int u = (t >= off) ? s[t-off] : 0; __syncthreads();
    s[t] += u; __syncthreads();
  }
  if (t < 196) bsum[t] = s[t] - v;   // exclusive
}
__global__ void k_scan3(int* __restrict__ exc, const int* __restrict__ bsum){
  const int i = blockIdx.x*256 + threadIdx.x;
  if (i < NN) exc[i] += bsum[blockIdx.x];
}
__global__ void k_perm(const int* __restrict__ gI, const int* __restrict__ gJ,
                       int* __restrict__ cur, int* __restrict__ iso,
                       int* __restrict__ jso){
  int e = blockIdx.x*256 + threadIdx.x;
  if (e < NE){
    int j = gJ[e];
    int p = atomicAdd(&cur[j], 1);
    iso[p] = gI[e]; jso[p] = j;
  }
}

// one MLP layer's MFMA sweep with GLOBAL-streamed B-fragments (2-deep prefetch).
// Weights stay in L2 (256KB total, all blocks share) — frees ~112 VGPRs/wave
// vs register-resident fragments, buying a 3rd co-resident block (R9 lesson:
// unified VGPR+AGPR file, not LDS, was the occupancy limiter).
// p = wfg + (w*2)*64 + lane; frag(kk,n) at p[kk*512 + n*64].
template<int SH, int KK>
__device__ __forceinline__ void layer_mm_g(const unsigned char* lbase,
                                           const short8* __restrict__ p,
                                           f32x4 (&acc)[4][2],
                                           int l15, int l4){
  short8 b0 = p[0], b1 = p[64];
#pragma unroll
  for (int kk=0; kk<KK; ++kk){
    short8 n0, n1;
    if (kk+1 < KK){ n0 = p[(kk+1)*512]; n1 = p[(kk+1)*512 + 64]; }
    short8 a[4];
#pragma unroll
    for (int m=0;m<4;++m){
      const int row = m*16 + l15;
      const int col = kk*32 + l4*8;
      const int c = (col>>3) ^ (row&7);
      a[m] = *(const short8*)(lbase + (row<<SH) + (c<<4));
    }
    __builtin_amdgcn_s_setprio(1);
#pragma unroll
    for (int m=0;m<4;++m){
      acc[m][0] = MFMA16(a[m], b0, acc[m][0]);
      acc[m][1] = MFMA16(a[m], b1, acc[m][1]);
    }
    __builtin_amdgcn_s_setprio(0);
    b0 = n0; b1 = n1;
  }
}
__device__ __forceinline__ void zero_acc(f32x4 (&acc)[4][2]){
#pragma unroll
  for (int m=0;m<4;++m)
#pragma unroll
    for (int n=0;n<2;++n){ f32x4 z = {0.f,0.f,0.f,0.f}; acc[m][n] = z; }
}
// C/D mapping: col = lane&15, row = (lane>>4)*4 + reg
__device__ __forceinline__ void store_h(unsigned char* hbase, f32x4 (&acc)[4][2],
                                        const float* b, bool relu,
                                        int w, int l15, int l4){
#pragma unroll
  for (int m=0;m<4;++m)
#pragma unroll
    for (int r=0;r<4;++r){
      const int row = m*16 + l4*4 + r;
#pragma unroll
      for (int n=0;n<2;++n){
        float v = acc[m][n][r] + b[n];
        if (relu) v = fmaxf(v, 0.f);
        *(u16*)(hbase + addrH(row, w*32 + n*16 + l15)) = f2bf(v);
      }
    }
}

// parallel 16-row LN stats: lane (l&15)=row offset, (l>>4)=32-col block.
__device__ __forceinline__ void ln_stats(unsigned char* lds_, int w, int l15, int l4){
  const int row = w*16 + l15;
  float s = 0.f, qs = 0.f;
#pragma unroll
  for (int q=0; q<4; ++q){
    short8 v8 = *(const short8*)(lds_ + H_OFF + addrH(row, l4*32 + q*8));
#pragma unroll
    for (int e2=0; e2<8; ++e2){
      float f = bf2f((u16)v8[e2]);
      s += f; qs += f*f;
    }
  }
  s  += __shfl_xor(s, 16);  qs += __shfl_xor(qs, 16);
  s  += __shfl_xor(s, 32);  qs += __shfl_xor(qs, 32);
  if (l4 == 0){
    float mean = s * (1.f/128.f);
    float var  = qs * (1.f/128.f) - mean*mean;
    float rstd = rsqrtf(var + 1e-5f);
    *(float2*)(lds_ + SMR_OFF + row*8) = make_float2(mean, rstd);
  }
}

// ---------------- edge kernel (sorted-by-j edges) ----------------
__global__ __launch_bounds__(256, 2)
void edge_kernel(const u16* __restrict__ xbf, const float* __restrict__ pos,
                 const int* __restrict__ iso, const int* __restrict__ jso,
                 const short8* __restrict__ wf0, const short8* __restrict__ wf1,
                 const short8* __restrict__ wf2,
                 const float* __restrict__ ew0_raw,
                 const float* __restrict__ eb0, const float* __restrict__ eb1,
                 const float* __restrict__ eb2, const float* __restrict__ eg,
                 const float* __restrict__ ebeta,
                 float* aggr)
{
  __shared__ alignas(16) unsigned char lds[LDS_SZ];
  const int tid = threadIdx.x;
  const int w = tid >> 6, lane = tid & 63;
  const int l15 = lane & 15, l4 = lane >> 4;
  const int h = lane >> 5, l31 = lane & 31;

  // per-wave streamed-fragment base pointers (weights live in L2)
  const short8* p0 = wf0 + (w*2)*64 + lane;
  const short8* p1 = wf1 + (w*2)*64 + lane;
  const short8* p2 = wf2 + (w*2)*64 + lane;

  float w4c[2][4];
#pragma unroll
  for (int n=0;n<2;++n)
#pragma unroll
    for (int q=0;q<4;++q) w4c[n][q] = ew0_raw[q*DD + w*32 + n*16 + l15];
  const float b0c[2] = { eb0[w*32 + l15], eb0[w*32 + 16 + l15] };
  const float b1c[2] = { eb1[w*32 + l15], eb1[w*32 + 16 + l15] };
  const float b2c[2] = { eb2[w*32 + l15], eb2[w*32 + 16 + l15] };
  const float egA = eg[2*lane],    egB = eg[2*lane+1];
  const float ebA = ebeta[2*lane], ebB = ebeta[2*lane+1];

  // bijective chunked XCD swizzle (m204)
  const int p = blockIdx.x;
  const int qq_ = EB/8, rr_ = EB%8;            // 234, 3
  const int xcd = p & 7, bidx = p >> 3;
  const int lb = (xcd < rr_ ? xcd*(qq_+1) : rr_*(qq_+1) + (xcd-rr_)*qq_) + bidx;
  const int ebase = lb*TPB*64;                 // block's 320 contiguous sorted edges

  // --- prologue: stage tile 0 (gather -> LDS directly; indices from global) ---
  {
#pragma unroll
    for (int it=0; it<16; ++it){
      const int slab = ebase + w*16 + it;
      const int ridx = h ? jso[slab] : iso[slab];
      s16x4 v = ((const s16x4*)(xbf + (size_t)ridx*DD))[l31];
      *(s16x4*)(lds + A_OFF + addrA(w*16+it, h*128 + l31*4)) = v;
    }
    if (tid < 64){
      const int ii = iso[ebase + tid], jj = jso[ebase + tid];
      float d0=pos[ii*3]-pos[jj*3], d1=pos[ii*3+1]-pos[jj*3+1], d2=pos[ii*3+2]-pos[jj*3+2];
      float nr=sqrtf(d0*d0+d1*d1+d2*d2);
      *(float4*)(lds + F4_OFF + tid*16) = make_float4(d0,d1,d2,nr);
    }
  }
  BAR();

  float a0 = 0.f, a1 = 0.f; int cj = -1;

  for (int tt = 0; tt < TPB; ++tt){
    f32x4 acc[4][2];
    // ---- P1: L0 (A + rank-4 pos part -> h0)
    zero_acc(acc);
    layer_mm_g<9,8>(lds + A_OFF, p0, acc, l15, l4);
#pragma unroll
    for (int m=0;m<4;++m)
#pragma unroll
      for (int r=0;r<4;++r){
        const int row = m*16 + l4*4 + r;
        float4 f = *(const float4*)(lds + F4_OFF + row*16);
#pragma unroll
        for (int n=0;n<2;++n)
          acc[m][n][r] += f.x*w4c[n][0] + f.y*w4c[n][1] + f.z*w4c[n][2] + f.w*w4c[n][3];
      }
    store_h(lds + H_OFF, acc, b0c, true, w, l15, l4);
    BAR();
    // ---- P2: L1 (h0 -> h1 in A region)
    zero_acc(acc);
    layer_mm_g<8,4>(lds + H_OFF, p1, acc, l15, l4);
    store_h(lds + A_OFF, acc, b1c, true, w, l15, l4);
    BAR();
    // ---- P3: L2 (h1 -> h2 in H region)
    zero_acc(acc);
    layer_mm_g<8,4>(lds + A_OFF, p2, acc, l15, l4);
    store_h(lds + H_OFF, acc, b2c, false, w, l15, l4);
    BAR();
    // ---- P4: stage next tile (A free; overlaps LN VALU work),
    //          parallel LN stats, batched o-compute, run-merged flush
    if (tt+1 < TPB){
      const int nb = ebase + (tt+1)*64;
#pragma unroll
      for (int it=0; it<16; ++it){
        const int slab = nb + w*16 + it;
        const int ridx = h ? jso[slab] : iso[slab];
        s16x4 v = ((const s16x4*)(xbf + (size_t)ridx*DD))[l31];
        *(s16x4*)(lds + A_OFF + addrA(w*16+it, h*128 + l31*4)) = v;
      }
      if (tid < 64){
        const int ii = iso[nb + tid], jj = jso[nb + tid];
        float d0=pos[ii*3]-pos[jj*3], d1=pos[ii*3+1]-pos[jj*3+1], d2=pos[ii*3+2]-pos[jj*3+2];
        float nr=sqrtf(d0*d0+d1*d1+d2*d2);
        *(float4*)(lds + F4_OFF + tid*16) = make_float4(d0,d1,d2,nr);
      }
    }
    ln_stats(lds, w, l15, l4);
#pragma unroll
    for (int half=0; half<2; ++half){
      float o0a[8], o1a[8]; int jja[8];
#pragma unroll
      for (int rr=0; rr<8; ++rr){
        const int row = w*16 + half*8 + rr;
        unsigned pk = *(const unsigned*)(lds + H_OFF + addrH(row, 2*lane));
        float2 mr = *(const float2*)(lds + SMR_OFF + row*8);
        float v0 = bf2f(pk & 0xffffu), v1 = bf2f(pk >> 16);
        o0a[rr] = (v0 - mr.x)*mr.y*egA + ebA;
        o1a[rr] = (v1 - mr.x)*mr.y*egB + ebB;
        jja[rr] = jso[ebase + tt*64 + row];      // wave-uniform, L2-hot
      }
#pragma unroll
      for (int rr=0; rr<8; ++rr){
        const int jj = jja[rr];
        if (jj != cj){
          if (cj >= 0){
            float* dst = aggr + (size_t)cj*DD + 2*lane;
            unsafeAtomicAdd(dst,     a0);
            unsafeAtomicAdd(dst + 1, a1);
          }
          cj = jj; a0 = o0a[rr]; a1 = o1a[rr];
        } else { a0 += o0a[rr]; a1 += o1a[rr]; }
      }
    }
    BAR();
  }
  if (cj >= 0){
    float* dst = aggr + (size_t)cj*DD + 2*lane;
    unsafeAtomicAdd(dst,     a0);
    unsafeAtomicAdd(dst + 1, a1);
  }
}

// ---------------- node kernel ----------------
#define SMR_OFF_N 49152
__global__ __launch_bounds__(256, 2)
void node_kernel(const u16* __restrict__ xbf, const float* __restrict__ x,
                 const short8* __restrict__ wf0, const short8* __restrict__ wf1,
                 const short8* __restrict__ wf2,
                 const float* __restrict__ nb0, const float* __restrict__ nb1,
                 const float* __restrict__ nb2, const float* __restrict__ ng,
                 const float* __restrict__ nbeta,
                 float* nio)
{
  __shared__ alignas(16) unsigned char lds[49664];
  const int tid = threadIdx.x;
  const int w = tid >> 6, lane = tid & 63;
  const int l15 = lane & 15, l4 = lane >> 4;
  const int h = lane >> 5, l31 = lane & 31;

  const short8* p0 = wf0 + (w*2)*64 + lane;
  const short8* p1 = wf1 + (w*2)*64 + lane;
  const short8* p2 = wf2 + (w*2)*64 + lane;

  const float b0c[2] = { nb0[w*32 + l15], nb0[w*32 + 16 + l15] };
  const float b1c[2] = { nb1[w*32 + l15], nb1[w*32 + 16 + l15] };
  const float b2c[2] = { nb2[w*32 + l15], nb2[w*32 + 16 + l15] };
  const float ngA = ng[2*lane],    ngB = ng[2*lane+1];
  const float nbA = nbeta[2*lane], nbB = nbeta[2*lane+1];

  for (int t = blockIdx.x; t < NTILES; t += gridDim.x){
    const int n0 = t*64;
#pragma unroll
    for (int it=0; it<16; ++it){
      const int rloc = w*16 + it;
      const int row = n0 + rloc;
      s16x4 v;
      if (h == 0){
        if (row < NN) v = ((const s16x4*)(xbf + (size_t)row*DD))[l31];
        else { v[0]=0; v[1]=0; v[2]=0; v[3]=0; }
      } else {
        if (row < NN){
          float4 f = ((const float4*)(nio + (size_t)row*DD))[l31];
          v[0]=(short)f2bf(f.x); v[1]=(short)f2bf(f.y);
          v[2]=(short)f2bf(f.z); v[3]=(short)f2bf(f.w);
        } else { v[0]=0; v[1]=0; v[2]=0; v[3]=0; }
      }
      *(s16x4*)(lds + A_OFF + addrA(rloc, h*128 + l31*4)) = v;
    }
    __syncthreads();

    f32x4 acc[4][2];
    zero_acc(acc);
    layer_mm_g<9,8>(lds + A_OFF, p0, acc, l15, l4);
    store_h(lds + H_OFF, acc, b0c, true, w, l15, l4);
    __syncthreads();
    zero_acc(acc);
    layer_mm_g<8,4>(lds + H_OFF, p1, acc, l15, l4);
    store_h(lds + A_OFF, acc, b1c, true, w, l15, l4);
    __syncthreads();
    zero_acc(acc);
    layer_mm_g<8,4>(lds + A_OFF, p2, acc, l15, l4);
    store_h(lds + H_OFF, acc, b2c, false, w, l15, l4);
    __syncthreads();
    // ---- parallel LN stats (write smr) then independent output rows
    {
      const int row = w*16 + l15;
      float s = 0.f, qs = 0.f;
#pragma unroll
      for (int q=0; q<4; ++q){
        short8 v8 = *(const short8*)(lds + H_OFF + addrH(row, l4*32 + q*8));
#pragma unroll
        for (int e2=0; e2<8; ++e2){
          float f = bf2f((u16)v8[e2]);
          s += f; qs += f*f;
        }
      }
      s  += __shfl_xor(s, 16);  qs += __shfl_xor(qs, 16);
      s  += __shfl_xor(s, 32);  qs += __shfl_xor(qs, 32);
      if (l4 == 0){
        float mean = s * (1.f/128.f);
        float var  = qs * (1.f/128.f) - mean*mean;
        float rstd = rsqrtf(var + 1e-5f);
        *(float2*)(lds + SMR_OFF_N + row*8) = make_float2(mean, rstd);
      }
    }
#pragma unroll
    for (int half=0; half<2; ++half){
#pragma unroll
      for (int rr=0; rr<8; ++rr){
        const int rloc = w*16 + half*8 + rr;
        const int row = n0 + rloc;
        if (row < NN){
          unsigned pk = *(const unsigned*)(lds + H_OFF + addrH(rloc, 2*lane));
          float2 mr = *(const float2*)(lds + SMR_OFF_N + rloc*8);
          f32x2 xr = *(const f32x2*)(x + (size_t)row*DD + 2*lane);
          float v0 = bf2f(pk & 0xffffu), v1 = bf2f(pk >> 16);
          f32x2 o;
          o[0] = (v0 - mr.x)*mr.y*ngA + nbA + xr[0];
          o[1] = (v1 - mr.x)*mr.y*ngB + nbB + xr[1];
          *(f32x2*)(nio + (size_t)row*DD + 2*lane) = o;
        }
      }
    }
    __syncthreads();
  }
}

extern "C" void kernel_launch(void* const* d_in, const int* in_sizes, int n_in,
                              void* d_out, int out_size, void* d_ws, size_t ws_size,
                              hipStream_t stream) {
  const float* x     = (const float*)d_in[0];
  const float* pos   = (const float*)d_in[1];
  const int*   g     = (const int*)  d_in[2];
  const float* ew0   = (const float*)d_in[3];
  const float* eb0   = (const float*)d_in[4];
  const float* ew1   = (const float*)d_in[5];
  const float* eb1   = (const float*)d_in[6];
  const float* ew2   = (const float*)d_in[7];
  const float* eb2   = (const float*)d_in[8];
  const float* eg    = (const float*)d_in[9];
  const float* ebeta = (const float*)d_in[10];
  const float* nw0   = (const float*)d_in[11];
  const float* nb0   = (const float*)d_in[12];
  const float* nw1   = (const float*)d_in[13];
  const float* nb1   = (const float*)d_in[14];
  const float* nw2   = (const float*)d_in[15];
  const float* nb2   = (const float*)d_in[16];
  const float* ng    = (const float*)d_in[17];
  const float* nbeta = (const float*)d_in[18];
  float* out  = (float*)d_out;
  u16*   ws   = (u16*)d_ws;
  int*   wsi  = (int*)d_ws;

  const int* gI = g;
  const int* gJ = g + NE;

  // x -> bf16 cache + weight fragment repack
  k_xbf<<<dim3(3125), dim3(256), 0, stream>>>(x, ws + XBF_U);
  repack_all<<<dim3(256), dim3(64), 0, stream>>>(ew0, ew1, ew2, nw0, nw1, nw2, ws);

  // counting sort of edges by j
  hipMemsetAsync(wsi + CNT_I, 0, NN*sizeof(int), stream);
  k_hist <<<dim3((NE+255)/256), dim3(256), 0, stream>>>(gJ, wsi + CNT_I);
  k_scan1<<<dim3(196), dim3(256), 0, stream>>>(wsi + CNT_I, wsi + CUR_I, wsi + BSUM_I);
  k_scan2<<<dim3(1), dim3(256), 0, stream>>>(wsi + BSUM_I);
  k_scan3<<<dim3(196), dim3(256), 0, stream>>>(wsi + CUR_I, wsi + BSUM_I);
  k_perm <<<dim3((NE+255)/256), dim3(256), 0, stream>>>(gI, gJ, wsi + CUR_I,
                                                        wsi + ISORT_I, wsi + JSORT_I);

  // aggr accumulator lives in d_out; zero it
  hipMemsetAsync(d_out, 0, (size_t)NN * DD * sizeof(float), stream);

  edge_kernel<<<dim3(EB), dim3(256), 0, stream>>>(
      ws + XBF_U, pos, wsi + ISORT_I, wsi + JSORT_I,
      (const short8*)(ws), (const short8*)(ws + 32768), (const short8*)(ws + 49152),
      ew0, eb0, eb1, eb2, eg, ebeta, out);

  node_kernel<<<dim3(NTILES), dim3(256), 0, stream>>>(
      ws + XBF_U, x,
      (const short8*)(ws + 65536), (const short8*)(ws + 98304), (const short8*)(ws + 114688),
      nb0, nb1, nb2, ng, nbeta, out);
}